// Round 10
// baseline (5524.787 us; speedup 1.0000x reference)
//
#include <hip/hip_runtime.h>

#define BB 64
#define TT 2048
#define FF 15
#define UU 256
#define N3 768

typedef _Float16 half8 __attribute__((ext_vector_type(8)));
typedef float f32x4 __attribute__((ext_vector_type(4)));

__device__ _Float16 g_seq1[BB * TT * UU];          // 67 MB (f16)
__device__ _Float16 g_xp[(size_t)BB * TT * N3];    // 201 MB (f16, xp1 then xp2)
__device__ uint4 g_U1p[48 * 8 * 64];               // 48 n-tiles x 8 k-tiles x 64 lanes x 16B
__device__ uint4 g_U2p[48 * 8 * 64];
__device__ uint4 g_W2p[48 * 8 * 64];               // W2 in the same fragment layout

// Pack a 256x768 fp32 matrix into per-lane MFMA B-fragments (f16).
// Fragment (nt, kt), lane l, dword d holds {M[kt*32+8*(l>>4)+2d][nt*16+(l&15)],
// M[...+2d+1][...]}. k-mapping f(l,i)=8*(l>>4)+i matches the A-side builds.
__global__ __launch_bounds__(256) void prep_upk(const float* __restrict__ U,
                                                unsigned* __restrict__ Up) {
    int idx = blockIdx.x * 256 + threadIdx.x;    // 0 .. 98303
    int d = idx & 3, l = (idx >> 2) & 63, kt = (idx >> 8) & 7, nt = idx >> 11;
    int row = kt * 32 + ((l >> 4) << 3) + 2 * d;
    int col = nt * 16 + (l & 15);
    unsigned short lo = __builtin_bit_cast(unsigned short, (_Float16)U[row * N3 + col]);
    unsigned short hi = __builtin_bit_cast(unsigned short, (_Float16)U[(row + 1) * N3 + col]);
    Up[idx] = (unsigned)lo | ((unsigned)hi << 16);
}

// xp1 = x @ W1 + b_in   (K=15, memory-bound), f16 output
__global__ __launch_bounds__(256) void gemm_k15(
    const float* __restrict__ x, const float* __restrict__ W1,
    const float* __restrict__ bin, _Float16* __restrict__ C) {
    __shared__ float xr[8][FF];
    const int m0 = blockIdx.x * 8;
    const int j  = blockIdx.y * 256 + threadIdx.x;
    if (threadIdx.x < 8 * FF) {
        int r = threadIdx.x / FF, k = threadIdx.x - r * FF;
        xr[r][k] = x[(size_t)(m0 + r) * FF + k];
    }
    __syncthreads();
    float wv[FF];
#pragma unroll
    for (int k = 0; k < FF; k++) wv[k] = W1[k * N3 + j];
    const float bj = bin[j];
#pragma unroll
    for (int r = 0; r < 8; r++) {
        float a = bj;
#pragma unroll
        for (int k = 0; k < FF; k++) a += xr[r][k] * wv[k];
        C[(size_t)(m0 + r) * N3 + j] = (_Float16)a;
    }
}

// xp2 = seq1 @ W2 + b_in  via f16 MFMA. M=131072, N=768, K=256.
// A-fragments loaded as half8 straight from the f16 seq1 (row = lane&15,
// k = kt*32 + 8*(lane>>4)+i -- the r9-validated mapping); B-fragments from
// L2-resident packed W2. f16 output.
__global__ __launch_bounds__(512) void gemm_xp_mfma(
    const _Float16* __restrict__ A, const uint4* __restrict__ Wp,
    const float* __restrict__ bin, _Float16* __restrict__ C) {
    const int tid = threadIdx.x, w = tid >> 6, lane = tid & 63;
    const int mt = w >> 1;                       // 0..3
    const int nb = (w & 1) * 24;                 // n-tile base
    const int arow = blockIdx.x * 64 + mt * 16 + (lane & 15);
    const int ko   = (lane >> 4) * 8;

    f32x4 acc[24] = {};
    const _Float16* ap = A + (size_t)arow * 256 + ko;

#pragma unroll
    for (int kt = 0; kt < 8; kt++) {
        half8 av = *(const half8*)(ap + kt * 32);
        const uint4* wp = Wp + (size_t)(nb * 8 + kt) * 64 + lane;
#pragma unroll
        for (int n = 0; n < 24; n++) {
            half8 bf = __builtin_bit_cast(half8, wp[(size_t)n * 8 * 64]);
            acc[n] = __builtin_amdgcn_mfma_f32_16x16x32_f16(av, bf, acc[n], 0, 0, 0);
        }
    }
    // D: col = lane&15, row-in-tile = (lane>>4)*4 + reg   (m89-verified)
    const int rbase = blockIdx.x * 64 + mt * 16 + (lane >> 4) * 4;
#pragma unroll
    for (int n = 0; n < 24; n++) {
        int col = (nb + n) * 16 + (lane & 15);
        float bv = bin[col];
#pragma unroll
        for (int d = 0; d < 4; d++)
            C[(size_t)(rbase + d) * N3 + col] = (_Float16)(acc[n][d] + bv);
    }
}

// ---------------- GRU recurrence (r6/r9-validated structure) -----------------
// One WG (512 thr, 8 waves) per batch element. rec = h(1x256) @ U(256x768) as
// 48 n-tiles x 8 k-tiles of 16x16x32 f16 MFMA; A = h broadcast -> all D rows
// identical -> lane holds col 16*nt+(lane&15) in acc reg 0. Wave w owns the
// z/r/hh tiles of units 32w..32w+31 -> gate math thread-local on all 8 waves,
// one barrier per step. r10 changes: (1) all 8 av fragments prefetched before
// the MFMA block (kills per-group ds_read latency bubbles in the MFMA issue
// stream); (2) chain-start MFMAs consume a hoisted zero srcC (no per-step acc
// zero-init movs); (3) r-chains first so exp(r) starts earliest; (4) xp read
// as f16.
__global__ __launch_bounds__(512) __attribute__((amdgpu_waves_per_eu(2, 2)))
void gru_mfma2(const uint4* __restrict__ Up, const float* __restrict__ brec,
               const _Float16* __restrict__ xp, _Float16* __restrict__ seq_out,
               float* __restrict__ state_out, float* __restrict__ extra_out) {
    const int b = blockIdx.x, tid = threadIdx.x;
    const int w = tid >> 6, lane = tid & 63;
    const int l15 = lane & 15;
    const int uA = 32 * w + l15, uB = uA + 16;

    __shared__ __align__(16) _Float16 h2s[2][UU];

    const int tz = 2 * w, tr = 16 + 2 * w, th = 32 + 2 * w;
    half8 ub[48];
#pragma unroll
    for (int kt = 0; kt < 8; kt++) {
        ub[0 * 8 + kt] = __builtin_bit_cast(half8, Up[((tz + 0) * 8 + kt) * 64 + lane]);
        ub[1 * 8 + kt] = __builtin_bit_cast(half8, Up[((tz + 1) * 8 + kt) * 64 + lane]);
        ub[2 * 8 + kt] = __builtin_bit_cast(half8, Up[((tr + 0) * 8 + kt) * 64 + lane]);
        ub[3 * 8 + kt] = __builtin_bit_cast(half8, Up[((tr + 1) * 8 + kt) * 64 + lane]);
        ub[4 * 8 + kt] = __builtin_bit_cast(half8, Up[((th + 0) * 8 + kt) * 64 + lane]);
        ub[5 * 8 + kt] = __builtin_bit_cast(half8, Up[((th + 1) * 8 + kt) * 64 + lane]);
    }
    const float brzA = brec[uA], brrA = brec[uA + UU], brhA = brec[uA + 2 * UU];
    const float brzB = brec[uB], brrB = brec[uB + UU], brhB = brec[uB + 2 * UU];

    if (tid < 128) ((unsigned*)h2s[0])[tid] = 0u;
    float hA = 0.f, hB = 0.f;
    __syncthreads();

    const _Float16* __restrict__ xpb = xp + (size_t)b * TT * N3;
    float xzA = (float)xpb[uA], xrA = (float)xpb[uA + UU], xhA = (float)xpb[uA + 2 * UU];
    float xzB = (float)xpb[uB], xrB = (float)xpb[uB + UU], xhB = (float)xpb[uB + 2 * UU];

    const int arow = (lane >> 4) << 3;
    const f32x4 kZ = {0.f, 0.f, 0.f, 0.f};       // hoisted zero srcC

    for (int t = 0; t < TT; t++) {
        const _Float16* xn = xpb + (size_t)(t + 1 < TT ? t + 1 : t) * N3;
        float xzAn = (float)xn[uA], xrAn = (float)xn[uA + UU], xhAn = (float)xn[uA + 2 * UU];
        float xzBn = (float)xn[uB], xrBn = (float)xn[uB + UU], xhBn = (float)xn[uB + 2 * UU];

        const _Float16* hcur = h2s[t & 1];
        // prefetch ALL av fragments up front (32 VGPRs), so the MFMA stream
        // has no interleaved LDS dependencies
        half8 av[8];
#pragma unroll
        for (int kt = 0; kt < 8; kt++)
            av[kt] = *(const half8*)&hcur[kt * 32 + arow];

        // chain starts (kt=0) with hoisted-zero srcC; r first, z last
        f32x4 a2 = __builtin_amdgcn_mfma_f32_16x16x32_f16(av[0], ub[2 * 8], kZ, 0, 0, 0);
        f32x4 a3 = __builtin_amdgcn_mfma_f32_16x16x32_f16(av[0], ub[3 * 8], kZ, 0, 0, 0);
        f32x4 a4 = __builtin_amdgcn_mfma_f32_16x16x32_f16(av[0], ub[4 * 8], kZ, 0, 0, 0);
        f32x4 a5 = __builtin_amdgcn_mfma_f32_16x16x32_f16(av[0], ub[5 * 8], kZ, 0, 0, 0);
        f32x4 a0 = __builtin_amdgcn_mfma_f32_16x16x32_f16(av[0], ub[0 * 8], kZ, 0, 0, 0);
        f32x4 a1 = __builtin_amdgcn_mfma_f32_16x16x32_f16(av[0], ub[1 * 8], kZ, 0, 0, 0);
#pragma unroll
        for (int kt = 1; kt < 8; kt++) {
            a2 = __builtin_amdgcn_mfma_f32_16x16x32_f16(av[kt], ub[2 * 8 + kt], a2, 0, 0, 0);
            a3 = __builtin_amdgcn_mfma_f32_16x16x32_f16(av[kt], ub[3 * 8 + kt], a3, 0, 0, 0);
            a4 = __builtin_amdgcn_mfma_f32_16x16x32_f16(av[kt], ub[4 * 8 + kt], a4, 0, 0, 0);
            a5 = __builtin_amdgcn_mfma_f32_16x16x32_f16(av[kt], ub[5 * 8 + kt], a5, 0, 0, 0);
            a0 = __builtin_amdgcn_mfma_f32_16x16x32_f16(av[kt], ub[0 * 8 + kt], a0, 0, 0, 0);
            a1 = __builtin_amdgcn_mfma_f32_16x16x32_f16(av[kt], ub[1 * 8 + kt], a1, 0, 0, 0);
        }

        float rA = 1.f / (1.f + __expf(-(xrA + a2[0] + brrA)));
        float rB = 1.f / (1.f + __expf(-(xrB + a3[0] + brrB)));
        float hhA = xhA + rA * (a4[0] + brhA); hhA = hhA > 0.f ? hhA : 0.f;
        float hhB = xhB + rB * (a5[0] + brhB); hhB = hhB > 0.f ? hhB : 0.f;
        float zA = 1.f / (1.f + __expf(-(xzA + a0[0] + brzA)));
        float zB = 1.f / (1.f + __expf(-(xzB + a1[0] + brzB)));
        hA = zA * hA + (1.f - zA) * hhA;
        hB = zB * hB + (1.f - zB) * hhB;

        _Float16* hnxt = h2s[(t + 1) & 1];
        if (lane < 32) {
            int   u  = (lane < 16) ? uA : uB;
            float hv = (lane < 16) ? hA : hB;
            _Float16 hq = (_Float16)hv;
            hnxt[u] = hq;
            if (seq_out)
                seq_out[(size_t)b * TT * UU + (size_t)t * UU + u] = hq;
        }
        __syncthreads();
        xzA = xzAn; xrA = xrAn; xhA = xhAn;
        xzB = xzBn; xrB = xrBn; xhB = xhBn;
    }

    if (lane < 32) {
        int   u  = (lane < 16) ? uA : uB;
        float hv = (lane < 16) ? hA : hB;
        state_out[b * UU + u] = hv;
        if (extra_out) extra_out[b * UU + u] = hv;
    }
}

extern "C" void kernel_launch(void* const* d_in, const int* in_sizes, int n_in,
                              void* d_out, int out_size, void* d_ws, size_t ws_size,
                              hipStream_t stream) {
    const float* x  = (const float*)d_in[0];
    const float* W1 = (const float*)d_in[1];
    const float* U1 = (const float*)d_in[2];
    const float* b1 = (const float*)d_in[3];
    const float* W2 = (const float*)d_in[4];
    const float* U2 = (const float*)d_in[5];
    const float* b2 = (const float*)d_in[6];
    float* out = (float*)d_out;

    uint4* U1p; hipGetSymbolAddress((void**)&U1p, HIP_SYMBOL(g_U1p));
    uint4* U2p; hipGetSymbolAddress((void**)&U2p, HIP_SYMBOL(g_U2p));
    uint4* W2p; hipGetSymbolAddress((void**)&W2p, HIP_SYMBOL(g_W2p));
    _Float16* seq1; hipGetSymbolAddress((void**)&seq1, HIP_SYMBOL(g_seq1));
    _Float16* xp;   hipGetSymbolAddress((void**)&xp,   HIP_SYMBOL(g_xp));

    prep_upk<<<384, 256, 0, stream>>>(U1, (unsigned*)U1p);
    prep_upk<<<384, 256, 0, stream>>>(U2, (unsigned*)U2p);
    prep_upk<<<384, 256, 0, stream>>>(W2, (unsigned*)W2p);

    // layer 1
    gemm_k15<<<dim3(BB * TT / 8, 3), 256, 0, stream>>>(x, W1, b1, xp);
    gru_mfma2<<<BB, 512, 0, stream>>>(U1p, b1 + N3, xp, seq1, out + BB * UU, nullptr);

    // layer 2
    gemm_xp_mfma<<<BB * TT / 64, 512, 0, stream>>>(seq1, W2p, b2, xp);
    gru_mfma2<<<BB, 512, 0, stream>>>(U2p, b2 + N3, xp, nullptr, out + 2 * BB * UU, out);
}

// Round 11
// 5066.781 us; speedup vs baseline: 1.0904x; 1.0904x over previous
//
#include <hip/hip_runtime.h>

#define BB 64
#define TT 2048
#define FF 15
#define UU 256
#define N3 768

typedef _Float16 half8 __attribute__((ext_vector_type(8)));
typedef float f32x4 __attribute__((ext_vector_type(4)));

__device__ _Float16 g_seq1[BB * TT * UU];          // 67 MB (f16)
__device__ _Float16 g_xp[(size_t)BB * TT * N3];    // 201 MB (f16, xp1 then xp2)
__device__ uint4 g_U1p[48 * 8 * 64];               // 48 n-tiles x 8 k-tiles x 64 lanes x 16B
__device__ uint4 g_U2p[48 * 8 * 64];
__device__ uint4 g_W2p[48 * 8 * 64];               // W2 in the same fragment layout

// Pack a 256x768 fp32 matrix into per-lane MFMA B-fragments (f16).
// Fragment (nt, kt), lane l, dword d holds {M[kt*32+8*(l>>4)+2d][nt*16+(l&15)],
// M[...+2d+1][...]}. k-mapping f(l,i)=8*(l>>4)+i matches the A-side builds.
__global__ __launch_bounds__(256) void prep_upk(const float* __restrict__ U,
                                                unsigned* __restrict__ Up) {
    int idx = blockIdx.x * 256 + threadIdx.x;    // 0 .. 98303
    int d = idx & 3, l = (idx >> 2) & 63, kt = (idx >> 8) & 7, nt = idx >> 11;
    int row = kt * 32 + ((l >> 4) << 3) + 2 * d;
    int col = nt * 16 + (l & 15);
    unsigned short lo = __builtin_bit_cast(unsigned short, (_Float16)U[row * N3 + col]);
    unsigned short hi = __builtin_bit_cast(unsigned short, (_Float16)U[(row + 1) * N3 + col]);
    Up[idx] = (unsigned)lo | ((unsigned)hi << 16);
}

// xp1 = x @ W1 + b_in   (K=15, memory-bound), f16 output
__global__ __launch_bounds__(256) void gemm_k15(
    const float* __restrict__ x, const float* __restrict__ W1,
    const float* __restrict__ bin, _Float16* __restrict__ C) {
    __shared__ float xr[8][FF];
    const int m0 = blockIdx.x * 8;
    const int j  = blockIdx.y * 256 + threadIdx.x;
    if (threadIdx.x < 8 * FF) {
        int r = threadIdx.x / FF, k = threadIdx.x - r * FF;
        xr[r][k] = x[(size_t)(m0 + r) * FF + k];
    }
    __syncthreads();
    float wv[FF];
#pragma unroll
    for (int k = 0; k < FF; k++) wv[k] = W1[k * N3 + j];
    const float bj = bin[j];
#pragma unroll
    for (int r = 0; r < 8; r++) {
        float a = bj;
#pragma unroll
        for (int k = 0; k < FF; k++) a += xr[r][k] * wv[k];
        C[(size_t)(m0 + r) * N3 + j] = (_Float16)a;
    }
}

// xp2 = seq1 @ W2 + b_in  via f16 MFMA. M=131072, N=768, K=256.
// A-fragments loaded as half8 straight from the f16 seq1 (row = lane&15,
// k = kt*32 + 8*(lane>>4)+i -- the r9-validated mapping); B-fragments from
// L2-resident packed W2. f16 output.
__global__ __launch_bounds__(512) void gemm_xp_mfma(
    const _Float16* __restrict__ A, const uint4* __restrict__ Wp,
    const float* __restrict__ bin, _Float16* __restrict__ C) {
    const int tid = threadIdx.x, w = tid >> 6, lane = tid & 63;
    const int mt = w >> 1;                       // 0..3
    const int nb = (w & 1) * 24;                 // n-tile base
    const int arow = blockIdx.x * 64 + mt * 16 + (lane & 15);
    const int ko   = (lane >> 4) * 8;

    f32x4 acc[24] = {};
    const _Float16* ap = A + (size_t)arow * 256 + ko;

#pragma unroll
    for (int kt = 0; kt < 8; kt++) {
        half8 av = *(const half8*)(ap + kt * 32);
        const uint4* wp = Wp + (size_t)(nb * 8 + kt) * 64 + lane;
#pragma unroll
        for (int n = 0; n < 24; n++) {
            half8 bf = __builtin_bit_cast(half8, wp[(size_t)n * 8 * 64]);
            acc[n] = __builtin_amdgcn_mfma_f32_16x16x32_f16(av, bf, acc[n], 0, 0, 0);
        }
    }
    // D: col = lane&15, row-in-tile = (lane>>4)*4 + reg   (m89-verified)
    const int rbase = blockIdx.x * 64 + mt * 16 + (lane >> 4) * 4;
#pragma unroll
    for (int n = 0; n < 24; n++) {
        int col = (nb + n) * 16 + (lane & 15);
        float bv = bin[col];
#pragma unroll
        for (int d = 0; d < 4; d++)
            C[(size_t)(rbase + d) * N3 + col] = (_Float16)(acc[n][d] + bv);
    }
}

// ---------------- GRU recurrence: EXACT r9 inner-loop structure --------------
// (r10's av[8]-prefetch + hoisted-zero-srcC restructure regressed 2265->2600
//  us/layer: the array prefetch walled ds_reads behind a conservative lgkmcnt
//  and broke the compiler's per-kt ds_read/MFMA interleave. Only the xp/seq
//  dtype (f16) is retained from r10 -- both outside the scheduling region.)
__global__ __launch_bounds__(512) __attribute__((amdgpu_waves_per_eu(2, 2)))
void gru_mfma2(const uint4* __restrict__ Up, const float* __restrict__ brec,
               const _Float16* __restrict__ xp, _Float16* __restrict__ seq_out,
               float* __restrict__ state_out, float* __restrict__ extra_out) {
    const int b = blockIdx.x, tid = threadIdx.x;
    const int w = tid >> 6, lane = tid & 63;
    const int l15 = lane & 15;
    const int uA = 32 * w + l15, uB = uA + 16;

    __shared__ __align__(16) _Float16 h2s[2][UU];

    const int tz = 2 * w, tr = 16 + 2 * w, th = 32 + 2 * w;
    half8 ub[48];
#pragma unroll
    for (int kt = 0; kt < 8; kt++) {
        ub[0 * 8 + kt] = __builtin_bit_cast(half8, Up[((tz + 0) * 8 + kt) * 64 + lane]);
        ub[1 * 8 + kt] = __builtin_bit_cast(half8, Up[((tz + 1) * 8 + kt) * 64 + lane]);
        ub[2 * 8 + kt] = __builtin_bit_cast(half8, Up[((tr + 0) * 8 + kt) * 64 + lane]);
        ub[3 * 8 + kt] = __builtin_bit_cast(half8, Up[((tr + 1) * 8 + kt) * 64 + lane]);
        ub[4 * 8 + kt] = __builtin_bit_cast(half8, Up[((th + 0) * 8 + kt) * 64 + lane]);
        ub[5 * 8 + kt] = __builtin_bit_cast(half8, Up[((th + 1) * 8 + kt) * 64 + lane]);
    }
    const float brzA = brec[uA], brrA = brec[uA + UU], brhA = brec[uA + 2 * UU];
    const float brzB = brec[uB], brrB = brec[uB + UU], brhB = brec[uB + 2 * UU];

    if (tid < 128) ((unsigned*)h2s[0])[tid] = 0u;
    float hA = 0.f, hB = 0.f;
    __syncthreads();

    const _Float16* __restrict__ xpb = xp + (size_t)b * TT * N3;
    float xzA = (float)xpb[uA], xrA = (float)xpb[uA + UU], xhA = (float)xpb[uA + 2 * UU];
    float xzB = (float)xpb[uB], xrB = (float)xpb[uB + UU], xhB = (float)xpb[uB + 2 * UU];

    const int arow = (lane >> 4) << 3;

    for (int t = 0; t < TT; t++) {
        const _Float16* xn = xpb + (size_t)(t + 1 < TT ? t + 1 : t) * N3;
        float xzAn = (float)xn[uA], xrAn = (float)xn[uA + UU], xhAn = (float)xn[uA + 2 * UU];
        float xzBn = (float)xn[uB], xrBn = (float)xn[uB + UU], xhBn = (float)xn[uB + 2 * UU];

        const _Float16* hcur = h2s[t & 1];
        f32x4 a0 = {0.f, 0.f, 0.f, 0.f}, a1 = a0, a2 = a0, a3 = a0, a4 = a0, a5 = a0;
#pragma unroll
        for (int kt = 0; kt < 8; kt++) {
            half8 av = *(const half8*)&hcur[kt * 32 + arow];
            a0 = __builtin_amdgcn_mfma_f32_16x16x32_f16(av, ub[0 * 8 + kt], a0, 0, 0, 0);
            a1 = __builtin_amdgcn_mfma_f32_16x16x32_f16(av, ub[1 * 8 + kt], a1, 0, 0, 0);
            a2 = __builtin_amdgcn_mfma_f32_16x16x32_f16(av, ub[2 * 8 + kt], a2, 0, 0, 0);
            a3 = __builtin_amdgcn_mfma_f32_16x16x32_f16(av, ub[3 * 8 + kt], a3, 0, 0, 0);
            a4 = __builtin_amdgcn_mfma_f32_16x16x32_f16(av, ub[4 * 8 + kt], a4, 0, 0, 0);
            a5 = __builtin_amdgcn_mfma_f32_16x16x32_f16(av, ub[5 * 8 + kt], a5, 0, 0, 0);
        }

        float zA = 1.f / (1.f + __expf(-(xzA + a0[0] + brzA)));
        float zB = 1.f / (1.f + __expf(-(xzB + a1[0] + brzB)));
        float rA = 1.f / (1.f + __expf(-(xrA + a2[0] + brrA)));
        float rB = 1.f / (1.f + __expf(-(xrB + a3[0] + brrB)));
        float hhA = xhA + rA * (a4[0] + brhA); hhA = hhA > 0.f ? hhA : 0.f;
        float hhB = xhB + rB * (a5[0] + brhB); hhB = hhB > 0.f ? hhB : 0.f;
        hA = zA * hA + (1.f - zA) * hhA;
        hB = zB * hB + (1.f - zB) * hhB;

        _Float16* hnxt = h2s[(t + 1) & 1];
        if (lane < 32) {
            int   u  = (lane < 16) ? uA : uB;
            float hv = (lane < 16) ? hA : hB;
            _Float16 hq = (_Float16)hv;
            hnxt[u] = hq;
            if (seq_out)
                seq_out[(size_t)b * TT * UU + (size_t)t * UU + u] = hq;
        }
        __syncthreads();
        xzA = xzAn; xrA = xrAn; xhA = xhAn;
        xzB = xzBn; xrB = xrBn; xhB = xhBn;
    }

    if (lane < 32) {
        int   u  = (lane < 16) ? uA : uB;
        float hv = (lane < 16) ? hA : hB;
        state_out[b * UU + u] = hv;
        if (extra_out) extra_out[b * UU + u] = hv;
    }
}

extern "C" void kernel_launch(void* const* d_in, const int* in_sizes, int n_in,
                              void* d_out, int out_size, void* d_ws, size_t ws_size,
                              hipStream_t stream) {
    const float* x  = (const float*)d_in[0];
    const float* W1 = (const float*)d_in[1];
    const float* U1 = (const float*)d_in[2];
    const float* b1 = (const float*)d_in[3];
    const float* W2 = (const float*)d_in[4];
    const float* U2 = (const float*)d_in[5];
    const float* b2 = (const float*)d_in[6];
    float* out = (float*)d_out;

    uint4* U1p; hipGetSymbolAddress((void**)&U1p, HIP_SYMBOL(g_U1p));
    uint4* U2p; hipGetSymbolAddress((void**)&U2p, HIP_SYMBOL(g_U2p));
    uint4* W2p; hipGetSymbolAddress((void**)&W2p, HIP_SYMBOL(g_W2p));
    _Float16* seq1; hipGetSymbolAddress((void**)&seq1, HIP_SYMBOL(g_seq1));
    _Float16* xp;   hipGetSymbolAddress((void**)&xp,   HIP_SYMBOL(g_xp));

    prep_upk<<<384, 256, 0, stream>>>(U1, (unsigned*)U1p);
    prep_upk<<<384, 256, 0, stream>>>(U2, (unsigned*)U2p);
    prep_upk<<<384, 256, 0, stream>>>(W2, (unsigned*)W2p);

    // layer 1
    gemm_k15<<<dim3(BB * TT / 8, 3), 256, 0, stream>>>(x, W1, b1, xp);
    gru_mfma2<<<BB, 512, 0, stream>>>(U1p, b1 + N3, xp, seq1, out + BB * UU, nullptr);

    // layer 2
    gemm_xp_mfma<<<BB * TT / 64, 512, 0, stream>>>(seq1, W2p, b2, xp);
    gru_mfma2<<<BB, 512, 0, stream>>>(U2p, b2 + N3, xp, nullptr, out + 2 * BB * UU, out);
}

// Round 12
// 4958.934 us; speedup vs baseline: 1.1141x; 1.0217x over previous
//
#include <hip/hip_runtime.h>

#define BB 64
#define TT 2048
#define FF 15
#define UU 256
#define N3 768

typedef _Float16 half8 __attribute__((ext_vector_type(8)));
typedef float f32x4 __attribute__((ext_vector_type(4)));

__device__ _Float16 g_seq1[BB * TT * UU];       // 67 MB (f16: free for gru store, halves GEMM A reads)
__device__ float g_xp[(size_t)BB * TT * N3];    // 402 MB (f32: gru scalar loads measured faster than f16)
__device__ uint4 g_U1p[48 * 8 * 64];            // 48 n-tiles x 8 k-tiles x 64 lanes x 16B
__device__ uint4 g_U2p[48 * 8 * 64];
__device__ uint4 g_W2p[48 * 8 * 64];            // W2 in the same fragment layout

// Pack a 256x768 fp32 matrix into per-lane MFMA B-fragments (f16).
// Fragment (nt, kt), lane l, dword d holds {M[kt*32+8*(l>>4)+2d][nt*16+(l&15)],
// M[...+2d+1][...]}. k-mapping f(l,i)=8*(l>>4)+i matches the A-side builds.
__global__ __launch_bounds__(256) void prep_upk(const float* __restrict__ U,
                                                unsigned* __restrict__ Up) {
    int idx = blockIdx.x * 256 + threadIdx.x;    // 0 .. 98303
    int d = idx & 3, l = (idx >> 2) & 63, kt = (idx >> 8) & 7, nt = idx >> 11;
    int row = kt * 32 + ((l >> 4) << 3) + 2 * d;
    int col = nt * 16 + (l & 15);
    unsigned short lo = __builtin_bit_cast(unsigned short, (_Float16)U[row * N3 + col]);
    unsigned short hi = __builtin_bit_cast(unsigned short, (_Float16)U[(row + 1) * N3 + col]);
    Up[idx] = (unsigned)lo | ((unsigned)hi << 16);
}

// xp1 = x @ W1 + b_in   (K=15, memory-bound), f32 output
__global__ __launch_bounds__(256) void gemm_k15(
    const float* __restrict__ x, const float* __restrict__ W1,
    const float* __restrict__ bin, float* __restrict__ C) {
    __shared__ float xr[8][FF];
    const int m0 = blockIdx.x * 8;
    const int j  = blockIdx.y * 256 + threadIdx.x;
    if (threadIdx.x < 8 * FF) {
        int r = threadIdx.x / FF, k = threadIdx.x - r * FF;
        xr[r][k] = x[(size_t)(m0 + r) * FF + k];
    }
    __syncthreads();
    float wv[FF];
#pragma unroll
    for (int k = 0; k < FF; k++) wv[k] = W1[k * N3 + j];
    const float bj = bin[j];
#pragma unroll
    for (int r = 0; r < 8; r++) {
        float a = bj;
#pragma unroll
        for (int k = 0; k < FF; k++) a += xr[r][k] * wv[k];
        C[(size_t)(m0 + r) * N3 + j] = a;
    }
}

// xp2 = seq1 @ W2 + b_in  via f16 MFMA. M=131072, N=768, K=256.
// A-fragments loaded as half8 straight from the f16 seq1 (row = lane&15,
// k = kt*32 + 8*(lane>>4)+i -- the r9-validated mapping); B-fragments from
// L2-resident packed W2. f32 output (gru reads xp as f32 scalars).
__global__ __launch_bounds__(512) void gemm_xp_mfma(
    const _Float16* __restrict__ A, const uint4* __restrict__ Wp,
    const float* __restrict__ bin, float* __restrict__ C) {
    const int tid = threadIdx.x, w = tid >> 6, lane = tid & 63;
    const int mt = w >> 1;                       // 0..3
    const int nb = (w & 1) * 24;                 // n-tile base
    const int arow = blockIdx.x * 64 + mt * 16 + (lane & 15);
    const int ko   = (lane >> 4) * 8;

    f32x4 acc[24] = {};
    const _Float16* ap = A + (size_t)arow * 256 + ko;

#pragma unroll
    for (int kt = 0; kt < 8; kt++) {
        half8 av = *(const half8*)(ap + kt * 32);
        const uint4* wp = Wp + (size_t)(nb * 8 + kt) * 64 + lane;
#pragma unroll
        for (int n = 0; n < 24; n++) {
            half8 bf = __builtin_bit_cast(half8, wp[(size_t)n * 8 * 64]);
            acc[n] = __builtin_amdgcn_mfma_f32_16x16x32_f16(av, bf, acc[n], 0, 0, 0);
        }
    }
    // D: col = lane&15, row-in-tile = (lane>>4)*4 + reg   (m89-verified)
    const int rbase = blockIdx.x * 64 + mt * 16 + (lane >> 4) * 4;
#pragma unroll
    for (int n = 0; n < 24; n++) {
        int col = (nb + n) * 16 + (lane & 15);
        float bv = bin[col];
#pragma unroll
        for (int d = 0; d < 4; d++)
            C[(size_t)(rbase + d) * N3 + col] = acc[n][d] + bv;
    }
}

// ---------------- GRU recurrence: EXACT r9 structure (fastest measured) ------
// One WG (512 thr, 8 waves) per batch element. rec = h(1x256) @ U(256x768) as
// 48 n-tiles x 8 k-tiles of 16x16x32 f16 MFMA; A = h broadcast -> all D rows
// identical -> lane holds col 16*nt+(lane&15) in acc reg 0. Wave w owns the
// z/r/hh tiles of units 32w..32w+31 -> gate math thread-local on all 8 waves,
// one barrier per step. xp is f32 (f16 scalar loads measured +125 us/layer,
// r11); seq_out is f16 (measured free, r11).
__global__ __launch_bounds__(512) __attribute__((amdgpu_waves_per_eu(2, 2)))
void gru_mfma2(const uint4* __restrict__ Up, const float* __restrict__ brec,
               const float* __restrict__ xp, _Float16* __restrict__ seq_out,
               float* __restrict__ state_out, float* __restrict__ extra_out) {
    const int b = blockIdx.x, tid = threadIdx.x;
    const int w = tid >> 6, lane = tid & 63;
    const int l15 = lane & 15;
    const int uA = 32 * w + l15, uB = uA + 16;

    __shared__ __align__(16) _Float16 h2s[2][UU];

    const int tz = 2 * w, tr = 16 + 2 * w, th = 32 + 2 * w;
    half8 ub[48];
#pragma unroll
    for (int kt = 0; kt < 8; kt++) {
        ub[0 * 8 + kt] = __builtin_bit_cast(half8, Up[((tz + 0) * 8 + kt) * 64 + lane]);
        ub[1 * 8 + kt] = __builtin_bit_cast(half8, Up[((tz + 1) * 8 + kt) * 64 + lane]);
        ub[2 * 8 + kt] = __builtin_bit_cast(half8, Up[((tr + 0) * 8 + kt) * 64 + lane]);
        ub[3 * 8 + kt] = __builtin_bit_cast(half8, Up[((tr + 1) * 8 + kt) * 64 + lane]);
        ub[4 * 8 + kt] = __builtin_bit_cast(half8, Up[((th + 0) * 8 + kt) * 64 + lane]);
        ub[5 * 8 + kt] = __builtin_bit_cast(half8, Up[((th + 1) * 8 + kt) * 64 + lane]);
    }
    const float brzA = brec[uA], brrA = brec[uA + UU], brhA = brec[uA + 2 * UU];
    const float brzB = brec[uB], brrB = brec[uB + UU], brhB = brec[uB + 2 * UU];

    if (tid < 128) ((unsigned*)h2s[0])[tid] = 0u;
    float hA = 0.f, hB = 0.f;
    __syncthreads();

    const float* __restrict__ xpb = xp + (size_t)b * TT * N3;
    float xzA = xpb[uA], xrA = xpb[uA + UU], xhA = xpb[uA + 2 * UU];
    float xzB = xpb[uB], xrB = xpb[uB + UU], xhB = xpb[uB + 2 * UU];

    const int arow = (lane >> 4) << 3;

    for (int t = 0; t < TT; t++) {
        const float* xn = xpb + (size_t)(t + 1 < TT ? t + 1 : t) * N3;
        float xzAn = xn[uA], xrAn = xn[uA + UU], xhAn = xn[uA + 2 * UU];
        float xzBn = xn[uB], xrBn = xn[uB + UU], xhBn = xn[uB + 2 * UU];

        const _Float16* hcur = h2s[t & 1];
        f32x4 a0 = {0.f, 0.f, 0.f, 0.f}, a1 = a0, a2 = a0, a3 = a0, a4 = a0, a5 = a0;
#pragma unroll
        for (int kt = 0; kt < 8; kt++) {
            half8 av = *(const half8*)&hcur[kt * 32 + arow];
            a0 = __builtin_amdgcn_mfma_f32_16x16x32_f16(av, ub[0 * 8 + kt], a0, 0, 0, 0);
            a1 = __builtin_amdgcn_mfma_f32_16x16x32_f16(av, ub[1 * 8 + kt], a1, 0, 0, 0);
            a2 = __builtin_amdgcn_mfma_f32_16x16x32_f16(av, ub[2 * 8 + kt], a2, 0, 0, 0);
            a3 = __builtin_amdgcn_mfma_f32_16x16x32_f16(av, ub[3 * 8 + kt], a3, 0, 0, 0);
            a4 = __builtin_amdgcn_mfma_f32_16x16x32_f16(av, ub[4 * 8 + kt], a4, 0, 0, 0);
            a5 = __builtin_amdgcn_mfma_f32_16x16x32_f16(av, ub[5 * 8 + kt], a5, 0, 0, 0);
        }

        float zA = 1.f / (1.f + __expf(-(xzA + a0[0] + brzA)));
        float zB = 1.f / (1.f + __expf(-(xzB + a1[0] + brzB)));
        float rA = 1.f / (1.f + __expf(-(xrA + a2[0] + brrA)));
        float rB = 1.f / (1.f + __expf(-(xrB + a3[0] + brrB)));
        float hhA = xhA + rA * (a4[0] + brhA); hhA = hhA > 0.f ? hhA : 0.f;
        float hhB = xhB + rB * (a5[0] + brhB); hhB = hhB > 0.f ? hhB : 0.f;
        hA = zA * hA + (1.f - zA) * hhA;
        hB = zB * hB + (1.f - zB) * hhB;

        _Float16* hnxt = h2s[(t + 1) & 1];
        if (lane < 32) {
            int   u  = (lane < 16) ? uA : uB;
            float hv = (lane < 16) ? hA : hB;
            _Float16 hq = (_Float16)hv;
            hnxt[u] = hq;
            if (seq_out)
                seq_out[(size_t)b * TT * UU + (size_t)t * UU + u] = hq;
        }
        __syncthreads();
        xzA = xzAn; xrA = xrAn; xhA = xhAn;
        xzB = xzBn; xrB = xrBn; xhB = xhBn;
    }

    if (lane < 32) {
        int   u  = (lane < 16) ? uA : uB;
        float hv = (lane < 16) ? hA : hB;
        state_out[b * UU + u] = hv;
        if (extra_out) extra_out[b * UU + u] = hv;
    }
}

extern "C" void kernel_launch(void* const* d_in, const int* in_sizes, int n_in,
                              void* d_out, int out_size, void* d_ws, size_t ws_size,
                              hipStream_t stream) {
    const float* x  = (const float*)d_in[0];
    const float* W1 = (const float*)d_in[1];
    const float* U1 = (const float*)d_in[2];
    const float* b1 = (const float*)d_in[3];
    const float* W2 = (const float*)d_in[4];
    const float* U2 = (const float*)d_in[5];
    const float* b2 = (const float*)d_in[6];
    float* out = (float*)d_out;

    uint4* U1p; hipGetSymbolAddress((void**)&U1p, HIP_SYMBOL(g_U1p));
    uint4* U2p; hipGetSymbolAddress((void**)&U2p, HIP_SYMBOL(g_U2p));
    uint4* W2p; hipGetSymbolAddress((void**)&W2p, HIP_SYMBOL(g_W2p));
    _Float16* seq1; hipGetSymbolAddress((void**)&seq1, HIP_SYMBOL(g_seq1));
    float* xp;      hipGetSymbolAddress((void**)&xp,   HIP_SYMBOL(g_xp));

    prep_upk<<<384, 256, 0, stream>>>(U1, (unsigned*)U1p);
    prep_upk<<<384, 256, 0, stream>>>(U2, (unsigned*)U2p);
    prep_upk<<<384, 256, 0, stream>>>(W2, (unsigned*)W2p);

    // layer 1
    gemm_k15<<<dim3(BB * TT / 8, 3), 256, 0, stream>>>(x, W1, b1, xp);
    gru_mfma2<<<BB, 512, 0, stream>>>(U1p, b1 + N3, xp, seq1, out + BB * UU, nullptr);

    // layer 2
    gemm_xp_mfma<<<BB * TT / 64, 512, 0, stream>>>(seq1, W2p, b2, xp);
    gru_mfma2<<<BB, 512, 0, stream>>>(U2p, b2 + N3, xp, nullptr, out + 2 * BB * UU, out);
}

// Round 13
// 4495.787 us; speedup vs baseline: 1.2289x; 1.1030x over previous
//
#include <hip/hip_runtime.h>

#define BB 64
#define TT 2048
#define FF 15
#define UU 256
#define N3 768

typedef _Float16 half8 __attribute__((ext_vector_type(8)));
typedef float f32x4 __attribute__((ext_vector_type(4)));

__device__ _Float16 g_seq1[BB * TT * UU];       // 67 MB (f16)
__device__ float g_xp[(size_t)BB * TT * N3];    // 402 MB (f32)
__device__ uint4 g_U1p[48 * 8 * 64];            // 48 n-tiles x 8 k-tiles x 64 lanes x 16B
__device__ uint4 g_U2p[48 * 8 * 64];
__device__ uint4 g_W2p[48 * 8 * 64];

// Pack a 256x768 fp32 matrix into per-lane MFMA B-fragments (f16).
// Fragment (nt, kt), lane l, dword d holds {M[kt*32+8*(l>>4)+2d][nt*16+(l&15)],
// M[...+2d+1][...]}. k-mapping f(l,i)=8*(l>>4)+i matches the A-side builds.
__global__ __launch_bounds__(256) void prep_upk(const float* __restrict__ U,
                                                unsigned* __restrict__ Up) {
    int idx = blockIdx.x * 256 + threadIdx.x;    // 0 .. 98303
    int d = idx & 3, l = (idx >> 2) & 63, kt = (idx >> 8) & 7, nt = idx >> 11;
    int row = kt * 32 + ((l >> 4) << 3) + 2 * d;
    int col = nt * 16 + (l & 15);
    unsigned short lo = __builtin_bit_cast(unsigned short, (_Float16)U[row * N3 + col]);
    unsigned short hi = __builtin_bit_cast(unsigned short, (_Float16)U[(row + 1) * N3 + col]);
    Up[idx] = (unsigned)lo | ((unsigned)hi << 16);
}

// xp1 = x @ W1 + b_in (+ b_rec folded for z,r columns)   (K=15, memory-bound)
__global__ __launch_bounds__(256) void gemm_k15(
    const float* __restrict__ x, const float* __restrict__ W1,
    const float* __restrict__ bin, const float* __restrict__ brec,
    float* __restrict__ C) {
    __shared__ float xr[8][FF];
    const int m0 = blockIdx.x * 8;
    const int j  = blockIdx.y * 256 + threadIdx.x;
    if (threadIdx.x < 8 * FF) {
        int r = threadIdx.x / FF, k = threadIdx.x - r * FF;
        xr[r][k] = x[(size_t)(m0 + r) * FF + k];
    }
    __syncthreads();
    float wv[FF];
#pragma unroll
    for (int k = 0; k < FF; k++) wv[k] = W1[k * N3 + j];
    const float bj = bin[j] + (j < 2 * UU ? brec[j] : 0.f);
#pragma unroll
    for (int r = 0; r < 8; r++) {
        float a = bj;
#pragma unroll
        for (int k = 0; k < FF; k++) a += xr[r][k] * wv[k];
        C[(size_t)(m0 + r) * N3 + j] = a;
    }
}

// xp2 = seq1 @ W2 + b_in (+ b_rec folded for z,r)  via f16 MFMA.
__global__ __launch_bounds__(512) void gemm_xp_mfma(
    const _Float16* __restrict__ A, const uint4* __restrict__ Wp,
    const float* __restrict__ bin, const float* __restrict__ brec,
    float* __restrict__ C) {
    const int tid = threadIdx.x, w = tid >> 6, lane = tid & 63;
    const int mt = w >> 1;
    const int nb = (w & 1) * 24;
    const int arow = blockIdx.x * 64 + mt * 16 + (lane & 15);
    const int ko   = (lane >> 4) * 8;

    f32x4 acc[24] = {};
    const _Float16* ap = A + (size_t)arow * 256 + ko;

#pragma unroll
    for (int kt = 0; kt < 8; kt++) {
        half8 av = *(const half8*)(ap + kt * 32);
        const uint4* wp = Wp + (size_t)(nb * 8 + kt) * 64 + lane;
#pragma unroll
        for (int n = 0; n < 24; n++) {
            half8 bf = __builtin_bit_cast(half8, wp[(size_t)n * 8 * 64]);
            acc[n] = __builtin_amdgcn_mfma_f32_16x16x32_f16(av, bf, acc[n], 0, 0, 0);
        }
    }
    const int rbase = blockIdx.x * 64 + mt * 16 + (lane >> 4) * 4;
#pragma unroll
    for (int n = 0; n < 24; n++) {
        int col = (nb + n) * 16 + (lane & 15);
        float bv = bin[col] + (col < 2 * UU ? brec[col] : 0.f);
#pragma unroll
        for (int d = 0; d < 4; d++)
            C[(size_t)(rbase + d) * N3 + col] = acc[n][d] + bv;
    }
}

// ---------------- GRU recurrence: 16 waves x 3 n-tiles ----------------------
// One WG (1024 thr, 16 waves) per batch element. Wave w owns the z/r/hh tiles
// of units 16w..16w+15 (tiles w, 16+w, 32+w): ub = 24 half8 = 96 regs, acc =
// 12, xp = 3+3, h = 1 -> ~125 regs, inside the 128-reg budget of 4 waves/SIMD
// (pinned). On the unified VGPR/AGPR file this removes any motive to home ub
// in AGPRs and shuttle it per-MFMA -- the suspected source of r12's ~800
// cyc/step of excess VALU issue. MFMA-issue floor unchanged (96/SIMD/step).
// brz/brr are folded into xp by the GEMM epilogues; only brh remains here.
__global__ __launch_bounds__(1024) __attribute__((amdgpu_waves_per_eu(4, 4)))
void gru_mfma16(const uint4* __restrict__ Up, const float* __restrict__ brec,
                const float* __restrict__ xp, _Float16* __restrict__ seq_out,
                float* __restrict__ state_out, float* __restrict__ extra_out) {
    const int b = blockIdx.x, tid = threadIdx.x;
    const int w = tid >> 6, lane = tid & 63;
    const int l15 = lane & 15;
    const int uA = 16 * w + l15;                   // this wave's unit range

    __shared__ __align__(16) _Float16 h2s[2][UU];

    // 24 B-fragments: z-tile w, r-tile 16+w, hh-tile 32+w, 8 k-tiles each
    half8 ub[24];
#pragma unroll
    for (int kt = 0; kt < 8; kt++) {
        ub[0 * 8 + kt] = __builtin_bit_cast(half8, Up[((w)      * 8 + kt) * 64 + lane]);
        ub[1 * 8 + kt] = __builtin_bit_cast(half8, Up[((16 + w) * 8 + kt) * 64 + lane]);
        ub[2 * 8 + kt] = __builtin_bit_cast(half8, Up[((32 + w) * 8 + kt) * 64 + lane]);
    }
    const float brh = brec[uA + 2 * UU];

    if (tid < 128) ((unsigned*)h2s[0])[tid] = 0u;
    float h = 0.f;
    __syncthreads();

    const float* __restrict__ xpb = xp + (size_t)b * TT * N3;
    float xz = xpb[uA], xr = xpb[uA + UU], xh = xpb[uA + 2 * UU];

    const int arow = (lane >> 4) << 3;

    for (int t = 0; t < TT; t++) {
        const float* xn = xpb + (size_t)(t + 1 < TT ? t + 1 : t) * N3;
        float xzn = xn[uA], xrn = xn[uA + UU], xhn = xn[uA + 2 * UU];

        const _Float16* hcur = h2s[t & 1];
        f32x4 a0 = {0.f, 0.f, 0.f, 0.f}, a1 = a0, a2 = a0;
#pragma unroll
        for (int kt = 0; kt < 8; kt++) {
            half8 av = *(const half8*)&hcur[kt * 32 + arow];
            a0 = __builtin_amdgcn_mfma_f32_16x16x32_f16(av, ub[0 * 8 + kt], a0, 0, 0, 0);
            a1 = __builtin_amdgcn_mfma_f32_16x16x32_f16(av, ub[1 * 8 + kt], a1, 0, 0, 0);
            a2 = __builtin_amdgcn_mfma_f32_16x16x32_f16(av, ub[2 * 8 + kt], a2, 0, 0, 0);
        }

        // gates (brz/brr pre-folded into xz/xr by the producer GEMM)
        float z  = 1.f / (1.f + __expf(-(xz + a0[0])));
        float r  = 1.f / (1.f + __expf(-(xr + a1[0])));
        float hh = xh + r * (a2[0] + brh);
        hh = hh > 0.f ? hh : 0.f;
        h = z * h + (1.f - z) * hh;

        _Float16* hnxt = h2s[(t + 1) & 1];
        if (lane < 16) {
            _Float16 hq = (_Float16)h;
            hnxt[uA] = hq;
            if (seq_out)
                seq_out[(size_t)b * TT * UU + (size_t)t * UU + uA] = hq;
        }
        __syncthreads();
        xz = xzn; xr = xrn; xh = xhn;
    }

    if (lane < 16) {
        state_out[b * UU + uA] = h;
        if (extra_out) extra_out[b * UU + uA] = h;
    }
}

extern "C" void kernel_launch(void* const* d_in, const int* in_sizes, int n_in,
                              void* d_out, int out_size, void* d_ws, size_t ws_size,
                              hipStream_t stream) {
    const float* x  = (const float*)d_in[0];
    const float* W1 = (const float*)d_in[1];
    const float* U1 = (const float*)d_in[2];
    const float* b1 = (const float*)d_in[3];
    const float* W2 = (const float*)d_in[4];
    const float* U2 = (const float*)d_in[5];
    const float* b2 = (const float*)d_in[6];
    float* out = (float*)d_out;

    uint4* U1p; hipGetSymbolAddress((void**)&U1p, HIP_SYMBOL(g_U1p));
    uint4* U2p; hipGetSymbolAddress((void**)&U2p, HIP_SYMBOL(g_U2p));
    uint4* W2p; hipGetSymbolAddress((void**)&W2p, HIP_SYMBOL(g_W2p));
    _Float16* seq1; hipGetSymbolAddress((void**)&seq1, HIP_SYMBOL(g_seq1));
    float* xp;      hipGetSymbolAddress((void**)&xp,   HIP_SYMBOL(g_xp));

    prep_upk<<<384, 256, 0, stream>>>(U1, (unsigned*)U1p);
    prep_upk<<<384, 256, 0, stream>>>(U2, (unsigned*)U2p);
    prep_upk<<<384, 256, 0, stream>>>(W2, (unsigned*)W2p);

    // layer 1 (b_rec z/r folded into xp by gemm_k15)
    gemm_k15<<<dim3(BB * TT / 8, 3), 256, 0, stream>>>(x, W1, b1, b1 + N3, xp);
    gru_mfma16<<<BB, 1024, 0, stream>>>(U1p, b1 + N3, xp, seq1, out + BB * UU, nullptr);

    // layer 2 (b_rec z/r folded into xp by gemm_xp_mfma)
    gemm_xp_mfma<<<BB * TT / 64, 512, 0, stream>>>(seq1, W2p, b2, b2 + N3, xp);
    gru_mfma16<<<BB, 1024, 0, stream>>>(U2p, b2 + N3, xp, nullptr, out + 2 * BB * UU, out);
}